// Round 14
// baseline (437.043 us; speedup 1.0000x reference)
//
#include <hip/hip_runtime.h>
#include <hip/hip_bf16.h>

// Problem constants (reference: B,S,H,D = 2,2048,32,128)
constexpr int Bc = 2;
constexpr int Sc = 2048;
constexpr int Hc = 32;
constexpr int Dc = 128;
constexpr int QKV_STRIDE = 3 * Hc * Dc;   // floats per (b, s) row: 12288

constexpr int BQ = 128;  // query rows per block (4 waves x 32 rows)
constexpr int BK = 64;   // kv rows per tile
constexpr float SCALE_LOG2E = 0.088388347648318f * 1.442695040888963f;
constexpr float DEFER_THR = 8.0f;   // T13

// LDS strides (shorts) — measured conflict-free (r4-r12: SQ_LDS_BANK_CONFLICT = 0)
constexpr int KST = 132;   // K row 264B
constexpr int VST = 68;    // V row 136B

// Pre-staged LDS-image layout in d_ws, one image per (bh, kv-tile):
//   K section  [64][KST] bf16 @ 0       (16896 B)
//   V^T section[128][VST] bf16 @ 16896  (17408 B)
//   pad to 36864 B (= 4 waves x 9 x 1KB global_load_lds rounds)
constexpr int V_OFF = 64 * KST * 2;              // 16896
constexpr int IMGB  = 36864;
constexpr size_t WS_NEED = (size_t)Bc * Hc * (Sc / BK) * IMGB;  // 2048 images

typedef __attribute__((ext_vector_type(8)))  short    bf16x8;
typedef __attribute__((ext_vector_type(4)))  short    bf16x4;
typedef __attribute__((ext_vector_type(16))) float    f32x16;
typedef __attribute__((ext_vector_type(4)))  unsigned u32x4;
typedef unsigned int u32;

static __device__ __forceinline__ short f2bf(float f) {
    __bf16 h = (__bf16)f;                  // RNE; pairs into v_cvt_pk_bf16_f32
    return __builtin_bit_cast(short, h);
}
static __device__ __forceinline__ unsigned pk2(float lo, float hi) {
    union { short2 s; unsigned u; } x;
    x.s.x = f2bf(lo); x.s.y = f2bf(hi);
    return x.u;
}
// v_permlane32_swap_b32 (verified r12): after plswap(dst, src):
//   new_dst = [dst_lo, src_lo], new_src = [dst_hi, src_hi]
// Operands must hold DIFFERENT values (equal operands may coalesce -> no-op).
static __device__ __forceinline__ void plswap(unsigned& dst, unsigned& src) {
    asm volatile("v_permlane32_swap_b32 %0, %1" : "+v"(dst), "+v"(src));
}
// Raw barrier (lgkm drain only).
static __device__ __forceinline__ void lds_barrier() {
    asm volatile("s_waitcnt lgkmcnt(0)" ::: "memory");
    __builtin_amdgcn_s_barrier();
    asm volatile("" ::: "memory");
}
// Direct global->LDS copy, 16B per lane; LDS dest = wave-uniform base + lane*16.
static __device__ __forceinline__ void glds16(const char* g, char* l) {
    __builtin_amdgcn_global_load_lds(
        (const __attribute__((address_space(1))) u32*)g,
        (__attribute__((address_space(3))) u32*)l, 16, 0, 0);
}

// ---------------- prepass: fp32 qkv -> bf16 LDS images in ws ----------------
__global__ __launch_bounds__(256)
void preconv(const float* __restrict__ qkv, char* __restrict__ ws)
{
    const int bid = blockIdx.x;        // bh*32 + kt
    const int bh = bid >> 5, kt = bid & 31;
    const int b = bh >> 5, h = bh & 31;
    char* img = ws + (size_t)bid * IMGB;

    const int t  = threadIdx.x;
    const int r  = t >> 2;             // key row in tile, 0..63
    const int cq = (t & 3) * 32;       // col base

    const float* kro = qkv + (size_t)(b * Sc + kt * 64 + r) * QKV_STRIDE
                       + Hc * Dc + h * Dc + cq;
    // K: 32 floats -> 32 bf16, row-major padded
    {
        short* kout = (short*)img + r * KST + cq;
        #pragma unroll
        for (int v = 0; v < 4; ++v) {
            float4 a = *(const float4*)(kro + v * 8);
            float4 c = *(const float4*)(kro + v * 8 + 4);
            bf16x8 pk;
            pk[0] = f2bf(a.x); pk[1] = f2bf(a.y); pk[2] = f2bf(a.z); pk[3] = f2bf(a.w);
            pk[4] = f2bf(c.x); pk[5] = f2bf(c.y); pk[6] = f2bf(c.z); pk[7] = f2bf(c.w);
            *(bf16x8*)(kout + v * 8) = pk;
        }
    }
    // V: stage fp32 tile to LDS (row stride 129: conflict-free column reads),
    // then write transposed bf16 rows.
    __shared__ float vt[64 * 129];
    {
        const float* vro = kro + Hc * Dc;
        #pragma unroll
        for (int v = 0; v < 8; ++v) {
            float4 a = *(const float4*)(vro + v * 4);
            float* dst = &vt[r * 129 + cq + v * 4];
            dst[0] = a.x; dst[1] = a.y; dst[2] = a.z; dst[3] = a.w;
        }
    }
    __syncthreads();
    {
        const int d = t >> 1, half = t & 1;
        short* vout = (short*)(img + V_OFF) + d * VST + half * 32;
        #pragma unroll
        for (int v = 0; v < 4; ++v) {
            bf16x8 pk;
            #pragma unroll
            for (int j = 0; j < 8; ++j)
                pk[j] = f2bf(vt[(half * 32 + v * 8 + j) * 129 + d]);
            *(bf16x8*)(vout + v * 8) = pk;
        }
    }
}

// ---------------- main kernel: glds staging + r12 compute core ----------------
__global__ __launch_bounds__(256)
void attn_ws(const char* __restrict__ ws,
             const int* __restrict__ causal_p,
             const float* __restrict__ qkv,
             float* __restrict__ out)
{
    // Work-balanced 1D grid (r7): bid = o*64 + bh; co-resident classes
    // {o,o+4,o+8,o+12} have equal total causal work.
    const int bid = blockIdx.x;
    const int o   = bid >> 6;
    const int bh  = bid & 63;
    const int r_  = o & 3;
    const int j_  = o >> 2;
    const int bq_ = 15 - 2 * r_;
    const int qt  = (j_ < 2) ? (bq_ - j_) : (15 - bq_ + 3 - j_);

    const int b = bh >> 5;
    const int h = bh & 31;
    const int causal = *causal_p;

    const int tid  = threadIdx.x;
    const int w    = tid >> 6;     // wave 0..3, owns 32 q rows
    const int lane = tid & 63;
    const int l31  = lane & 31;
    const int hf   = lane >> 5;

    __shared__ char lbuf[IMGB];
    short* Ks = (short*)lbuf;
    short* Vs = (short*)(lbuf + V_OFF);

    const int q0  = qt * BQ;
    const int wq0 = q0 + w * 32;

    const char* imgs = ws + (size_t)bh * 32 * IMGB;

    // ---- Q as swapped-QK B-fragments (fp32 source, once) ----
    bf16x8 qf[8];
    {
        const float* qb = qkv + (size_t)(b * Sc + wq0 + l31) * QKV_STRIDE + h * Dc;
        #pragma unroll
        for (int st = 0; st < 8; ++st) {
            const float* p = qb + st * 16 + hf * 8;
            float4 x0 = *(const float4*)(p);
            float4 x1 = *(const float4*)(p + 4);
            bf16x8 q;
            q[0] = f2bf(x0.x * SCALE_LOG2E);
            q[1] = f2bf(x0.y * SCALE_LOG2E);
            q[2] = f2bf(x0.z * SCALE_LOG2E);
            q[3] = f2bf(x0.w * SCALE_LOG2E);
            q[4] = f2bf(x1.x * SCALE_LOG2E);
            q[5] = f2bf(x1.y * SCALE_LOG2E);
            q[6] = f2bf(x1.z * SCALE_LOG2E);
            q[7] = f2bf(x1.w * SCALE_LOG2E);
            qf[st] = q;
        }
    }

    f32x16 o_[4];
    #pragma unroll
    for (int db = 0; db < 4; ++db)
        #pragma unroll
        for (int i = 0; i < 16; ++i) o_[db][i] = 0.f;
    float m = -1e30f, l = 0.f;

    const int nkv = causal ? (2 * qt + 2) : (Sc / BK);

    for (int kt = 0; kt < nkv; ++kt) {
        lds_barrier();                      // prev tile's readers done
        // stage: wave w copies its 9KB slice of the pre-built image
        {
            const char* src = imgs + (size_t)kt * IMGB + w * 9216 + lane * 16;
            char* dst = lbuf + w * 9216;    // wave-uniform
            #pragma unroll
            for (int i = 0; i < 9; ++i)
                glds16(src + i * 1024, dst + i * 1024);
        }
        asm volatile("s_waitcnt vmcnt(0)" ::: "memory");
        lds_barrier();                      // staged tile visible

        const int kbase = kt * BK;
        if (causal && kbase > wq0 + 31) continue;   // wave-uniform compute skip

        // ---- S^T = K Q^T ----
        f32x16 acc[2];
        #pragma unroll
        for (int mb = 0; mb < 2; ++mb)
            #pragma unroll
            for (int i = 0; i < 16; ++i) acc[mb][i] = 0.f;
        __builtin_amdgcn_s_setprio(1);
        #pragma unroll
        for (int st = 0; st < 8; ++st) {
            #pragma unroll
            for (int mb = 0; mb < 2; ++mb) {
                bf16x8 ka = *(const bf16x8*)&Ks[(mb * 32 + l31) * KST + st * 16 + hf * 8];
                acc[mb] = __builtin_amdgcn_mfma_f32_32x32x16_bf16(ka, qf[st], acc[mb], 0, 0, 0);
            }
        }
        __builtin_amdgcn_s_setprio(0);

        // ---- causal mask (straddle tiles only) ----
        if (causal && kbase + 63 > wq0) {
            const int qg = wq0 + l31;
            #pragma unroll
            for (int mb = 0; mb < 2; ++mb) {
                #pragma unroll
                for (int r = 0; r < 16; ++r) {
                    const int kgl = kbase + mb * 32 + (r & 3) + 8 * (r >> 2) + 4 * hf;
                    if (kgl > qg) acc[mb][r] = -1e30f;
                }
            }
        }

        // ---- online softmax (in-lane + cross-half); T13 defer ----
        float pm = acc[0][0];
        #pragma unroll
        for (int i = 1; i < 16; ++i) pm = fmaxf(pm, acc[0][i]);
        #pragma unroll
        for (int i = 0; i < 16; ++i) pm = fmaxf(pm, acc[1][i]);
        pm = fmaxf(pm, __shfl_xor(pm, 32));
        if (__any(pm > m + DEFER_THR)) {
            const float mnew  = fmaxf(m, pm);
            const float alpha = __builtin_amdgcn_exp2f(m - mnew);
            m = mnew; l *= alpha;
            #pragma unroll
            for (int r = 0; r < 16; ++r) {
                const float ar = __shfl(alpha, (r & 3) + 8 * (r >> 2) + 4 * hf);
                o_[0][r] *= ar; o_[1][r] *= ar; o_[2][r] *= ar; o_[3][r] *= ar;
            }
        }
        float rs = 0.f;
        #pragma unroll
        for (int i = 0; i < 16; ++i) {
            const float p = __builtin_amdgcn_exp2f(acc[0][i] - m);
            acc[0][i] = p; rs += p;
        }
        #pragma unroll
        for (int i = 0; i < 16; ++i) {
            const float p = __builtin_amdgcn_exp2f(acc[1][i] - m);
            acc[1][i] = p; rs += p;
        }
        rs += __shfl_xor(rs, 32);
        l += rs;

        // ---- P -> bf16 A-fragments: 16 cvt_pk + 8 permlane swaps (verified r12) ----
        unsigned wpk[2][4][2];
        #pragma unroll
        for (int mb = 0; mb < 2; ++mb)
            #pragma unroll
            for (int c = 0; c < 4; ++c) {
                wpk[mb][c][0] = pk2(acc[mb][4 * c + 0], acc[mb][4 * c + 1]);
                wpk[mb][c][1] = pk2(acc[mb][4 * c + 2], acc[mb][4 * c + 3]);
            }
        bf16x8 pa[4];
        #pragma unroll
        for (int ks = 0; ks < 4; ++ks) {
            const int mb = ks >> 1, ci = ks & 1;
            unsigned e0 = wpk[mb][2 * ci][0], o0 = wpk[mb][2 * ci + 1][0];
            unsigned e1 = wpk[mb][2 * ci][1], o1 = wpk[mb][2 * ci + 1][1];
            plswap(e0, o0);
            plswap(e1, o1);
            u32x4 wv;
            wv[0] = e0; wv[1] = e1; wv[2] = o0; wv[3] = o1;
            pa[ks] = __builtin_bit_cast(bf16x8, wv);
        }

        // ---- O += P V ----
        __builtin_amdgcn_s_setprio(1);
        #pragma unroll
        for (int ks = 0; ks < 4; ++ks) {
            #pragma unroll
            for (int db = 0; db < 4; ++db) {
                bf16x8 vb = *(const bf16x8*)&Vs[(db * 32 + l31) * VST + ks * 16 + hf * 8];
                o_[db] = __builtin_amdgcn_mfma_f32_32x32x16_bf16(pa[ks], vb, o_[db], 0, 0, 0);
            }
        }
        __builtin_amdgcn_s_setprio(0);
    }

    // ---- epilogue ----
    #pragma unroll
    for (int r = 0; r < 16; ++r) {
        const int rq = (r & 3) + 8 * (r >> 2) + 4 * hf;
        const float lr = __shfl(l, rq);
        const float inv = 1.f / lr;
        const int qg = wq0 + rq;
        float* ob = out + (size_t)(b * Sc + qg) * (Hc * Dc) + h * Dc + l31;
        ob[0]  = o_[0][r] * inv;
        ob[32] = o_[1][r] * inv;
        ob[64] = o_[2][r] * inv;
        ob[96] = o_[3][r] * inv;
    }
}

// ---------------- fallback: r12 kernel verbatim (used if ws too small) ----------------
__global__ __launch_bounds__(256)
void attn_fb(const float* __restrict__ qkv,
             const int* __restrict__ causal_p,
             float* __restrict__ out)
{
    const int bid = blockIdx.x;
    const int o   = bid >> 6;
    const int bh  = bid & 63;
    const int r_  = o & 3;
    const int j_  = o >> 2;
    const int bq_ = 15 - 2 * r_;
    const int qt  = (j_ < 2) ? (bq_ - j_) : (15 - bq_ + 3 - j_);

    const int b = bh >> 5;
    const int h = bh & 31;
    const int causal = *causal_p;

    const int tid  = threadIdx.x;
    const int w    = tid >> 6;
    const int lane = tid & 63;
    const int l31  = lane & 31;
    const int hf   = lane >> 5;

    __shared__ short Ks[64 * KST];
    __shared__ short Vs[128 * VST];

    const int q0  = qt * BQ;
    const int wq0 = q0 + w * 32;
    const int kg = tid >> 5;
    const int dl = tid & 31;

    const float* kplane = qkv + (size_t)b * Sc * QKV_STRIDE + Hc * Dc + h * Dc;

    bf16x8 qf[8];
    {
        const float* qb = qkv + (size_t)(b * Sc + wq0 + l31) * QKV_STRIDE + h * Dc;
        #pragma unroll
        for (int st = 0; st < 8; ++st) {
            const float* p = qb + st * 16 + hf * 8;
            float4 x0 = *(const float4*)(p);
            float4 x1 = *(const float4*)(p + 4);
            bf16x8 q;
            q[0] = f2bf(x0.x * SCALE_LOG2E);
            q[1] = f2bf(x0.y * SCALE_LOG2E);
            q[2] = f2bf(x0.z * SCALE_LOG2E);
            q[3] = f2bf(x0.w * SCALE_LOG2E);
            q[4] = f2bf(x1.x * SCALE_LOG2E);
            q[5] = f2bf(x1.y * SCALE_LOG2E);
            q[6] = f2bf(x1.z * SCALE_LOG2E);
            q[7] = f2bf(x1.w * SCALE_LOG2E);
            qf[st] = q;
        }
    }

    f32x16 o_[4];
    #pragma unroll
    for (int db = 0; db < 4; ++db)
        #pragma unroll
        for (int i = 0; i < 16; ++i) o_[db][i] = 0.f;
    float m = -1e30f, l = 0.f;

    const int nkv = causal ? (2 * qt + 2) : (Sc / BK);
    float4 kst[8];
    float  vst[8][4];

    auto issue = [&](int kt) {
        const float* kb = kplane + (size_t)(kt * BK + kg * 8) * QKV_STRIDE;
        #pragma unroll
        for (int j = 0; j < 8; ++j)
            kst[j] = *(const float4*)(kb + (size_t)j * QKV_STRIDE + dl * 4);
        const float* vb = kb + Hc * Dc;
        #pragma unroll
        for (int j = 0; j < 8; ++j) {
            #pragma unroll
            for (int q = 0; q < 4; ++q)
                vst[j][q] = vb[(size_t)j * QKV_STRIDE + q * 32 + dl];
        }
    };
    auto commit = [&]() {
        #pragma unroll
        for (int j = 0; j < 8; ++j) {
            bf16x4 kk;
            kk[0] = f2bf(kst[j].x); kk[1] = f2bf(kst[j].y);
            kk[2] = f2bf(kst[j].z); kk[3] = f2bf(kst[j].w);
            *(bf16x4*)&Ks[(kg * 8 + j) * KST + dl * 4] = kk;
        }
        #pragma unroll
        for (int q = 0; q < 4; ++q) {
            bf16x8 vv;
            #pragma unroll
            for (int j = 0; j < 8; ++j) vv[j] = f2bf(vst[j][q]);
            *(bf16x8*)&Vs[(q * 32 + dl) * VST + kg * 8] = vv;
        }
    };

    issue(0);
    for (int kt = 0; kt < nkv; ++kt) {
        lds_barrier();
        commit();
        if (kt + 1 < nkv) issue(kt + 1);
        lds_barrier();

        const int kbase = kt * BK;
        if (causal && kbase > wq0 + 31) continue;

        f32x16 acc[2];
        #pragma unroll
        for (int mb = 0; mb < 2; ++mb)
            #pragma unroll
            for (int i = 0; i < 16; ++i) acc[mb][i] = 0.f;
        __builtin_amdgcn_s_setprio(1);
        #pragma unroll
        for (int st = 0; st < 8; ++st) {
            #pragma unroll
            for (int mb = 0; mb < 2; ++mb) {
                bf16x8 ka = *(const bf16x8*)&Ks[(mb * 32 + l31) * KST + st * 16 + hf * 8];
                acc[mb] = __builtin_amdgcn_mfma_f32_32x32x16_bf16(ka, qf[st], acc[mb], 0, 0, 0);
            }
        }
        __builtin_amdgcn_s_setprio(0);

        if (causal && kbase + 63 > wq0) {
            const int qg = wq0 + l31;
            #pragma unroll
            for (int mb = 0; mb < 2; ++mb) {
                #pragma unroll
                for (int r = 0; r < 16; ++r) {
                    const int kgl = kbase + mb * 32 + (r & 3) + 8 * (r >> 2) + 4 * hf;
                    if (kgl > qg) acc[mb][r] = -1e30f;
                }
            }
        }

        float pm = acc[0][0];
        #pragma unroll
        for (int i = 1; i < 16; ++i) pm = fmaxf(pm, acc[0][i]);
        #pragma unroll
        for (int i = 0; i < 16; ++i) pm = fmaxf(pm, acc[1][i]);
        pm = fmaxf(pm, __shfl_xor(pm, 32));
        if (__any(pm > m + DEFER_THR)) {
            const float mnew  = fmaxf(m, pm);
            const float alpha = __builtin_amdgcn_exp2f(m - mnew);
            m = mnew; l *= alpha;
            #pragma unroll
            for (int r = 0; r < 16; ++r) {
                const float ar = __shfl(alpha, (r & 3) + 8 * (r >> 2) + 4 * hf);
                o_[0][r] *= ar; o_[1][r] *= ar; o_[2][r] *= ar; o_[3][r] *= ar;
            }
        }
        float rs = 0.f;
        #pragma unroll
        for (int i = 0; i < 16; ++i) {
            const float p = __builtin_amdgcn_exp2f(acc[0][i] - m);
            acc[0][i] = p; rs += p;
        }
        #pragma unroll
        for (int i = 0; i < 16; ++i) {
            const float p = __builtin_amdgcn_exp2f(acc[1][i] - m);
            acc[1][i] = p; rs += p;
        }
        rs += __shfl_xor(rs, 32);
        l += rs;

        unsigned wpk[2][4][2];
        #pragma unroll
        for (int mb = 0; mb < 2; ++mb)
            #pragma unroll
            for (int c = 0; c < 4; ++c) {
                wpk[mb][c][0] = pk2(acc[mb][4 * c + 0], acc[mb][4 * c + 1]);
                wpk[mb][c][1] = pk2(acc[mb][4 * c + 2], acc[mb][4 * c + 3]);
            }
        bf16x8 pa[4];
        #pragma unroll
        for (int ks = 0; ks < 4; ++ks) {
            const int mb = ks >> 1, ci = ks & 1;
            unsigned e0 = wpk[mb][2 * ci][0], o0 = wpk[mb][2 * ci + 1][0];
            unsigned e1 = wpk[mb][2 * ci][1], o1 = wpk[mb][2 * ci + 1][1];
            plswap(e0, o0);
            plswap(e1, o1);
            u32x4 wv;
            wv[0] = e0; wv[1] = e1; wv[2] = o0; wv[3] = o1;
            pa[ks] = __builtin_bit_cast(bf16x8, wv);
        }

        __builtin_amdgcn_s_setprio(1);
        #pragma unroll
        for (int ks = 0; ks < 4; ++ks) {
            #pragma unroll
            for (int db = 0; db < 4; ++db) {
                bf16x8 vb = *(const bf16x8*)&Vs[(db * 32 + l31) * VST + ks * 16 + hf * 8];
                o_[db] = __builtin_amdgcn_mfma_f32_32x32x16_bf16(pa[ks], vb, o_[db], 0, 0, 0);
            }
        }
        __builtin_amdgcn_s_setprio(0);
    }

    #pragma unroll
    for (int r = 0; r < 16; ++r) {
        const int rq = (r & 3) + 8 * (r >> 2) + 4 * hf;
        const float lr = __shfl(l, rq);
        const float inv = 1.f / lr;
        const int qg = wq0 + rq;
        float* ob = out + (size_t)(b * Sc + qg) * (Hc * Dc) + h * Dc + l31;
        ob[0]  = o_[0][r] * inv;
        ob[32] = o_[1][r] * inv;
        ob[64] = o_[2][r] * inv;
        ob[96] = o_[3][r] * inv;
    }
}

extern "C" void kernel_launch(void* const* d_in, const int* in_sizes, int n_in,
                              void* d_out, int out_size, void* d_ws, size_t ws_size,
                              hipStream_t stream) {
    const float* qkv = (const float*)d_in[0];
    const int* causal = (const int*)d_in[1];
    float* out = (float*)d_out;
    if (ws_size >= WS_NEED) {
        preconv<<<Bc * Hc * (Sc / BK), 256, 0, stream>>>(qkv, (char*)d_ws);
        attn_ws<<<(Sc / BQ) * Bc * Hc, 256, 0, stream>>>((const char*)d_ws, causal, qkv, out);
    } else {
        attn_fb<<<(Sc / BQ) * Bc * Hc, 256, 0, stream>>>(qkv, causal, out);
    }
}

// Round 15
// 408.611 us; speedup vs baseline: 1.0696x; 1.0696x over previous
//
#include <hip/hip_runtime.h>
#include <hip/hip_bf16.h>

// Problem constants (reference: B,S,H,D = 2,2048,32,128)
constexpr int Bc = 2;
constexpr int Sc = 2048;
constexpr int Hc = 32;
constexpr int Dc = 128;
constexpr int QKV_STRIDE = 3 * Hc * Dc;   // floats per (b, s) row: 12288

constexpr int BQ = 128;  // query rows per block (4 waves x 32 rows)
constexpr int BK = 64;   // kv rows per tile
constexpr float SCALE_LOG2E = 0.088388347648318f * 1.442695040888963f;
constexpr float DEFER_THR = 8.0f;   // T13

// LDS strides (shorts) — measured conflict-free (r4-r12: SQ_LDS_BANK_CONFLICT = 0)
constexpr int KST = 132;   // K row 264B
constexpr int VST = 68;    // V row 136B

// Pre-staged LDS-image layout in d_ws, one image per (bh, kv-tile):
//   K section  [64][KST] bf16 @ 0       (16896 B)
//   V^T section[128][VST] bf16 @ 16896  (17408 B)
//   pad to 36864 B (= 4 waves x 9 x 1KB global_load_lds rounds)
constexpr int V_OFF = 64 * KST * 2;              // 16896
constexpr int IMGB  = 36864;
constexpr size_t WS_NEED = (size_t)Bc * Hc * (Sc / BK) * IMGB;  // 2048 images

typedef __attribute__((ext_vector_type(8)))  short    bf16x8;
typedef __attribute__((ext_vector_type(4)))  short    bf16x4;
typedef __attribute__((ext_vector_type(16))) float    f32x16;
typedef __attribute__((ext_vector_type(4)))  unsigned u32x4;
typedef unsigned int u32;

static __device__ __forceinline__ short f2bf(float f) {
    __bf16 h = (__bf16)f;                  // RNE; pairs into v_cvt_pk_bf16_f32
    return __builtin_bit_cast(short, h);
}
static __device__ __forceinline__ unsigned pk2(float lo, float hi) {
    union { short2 s; unsigned u; } x;
    x.s.x = f2bf(lo); x.s.y = f2bf(hi);
    return x.u;
}
// v_permlane32_swap_b32 (verified r12): after plswap(dst, src):
//   new_dst = [dst_lo, src_lo], new_src = [dst_hi, src_hi]
// Operands must hold DIFFERENT values (equal operands may coalesce -> no-op).
static __device__ __forceinline__ void plswap(unsigned& dst, unsigned& src) {
    asm volatile("v_permlane32_swap_b32 %0, %1" : "+v"(dst), "+v"(src));
}
// Raw barrier (lgkm drain only).
static __device__ __forceinline__ void lds_barrier() {
    asm volatile("s_waitcnt lgkmcnt(0)" ::: "memory");
    __builtin_amdgcn_s_barrier();
    asm volatile("" ::: "memory");
}
// Direct global->LDS copy, 16B per lane; LDS dest = wave-uniform base + lane*16.
static __device__ __forceinline__ void glds16(const char* g, char* l) {
    __builtin_amdgcn_global_load_lds(
        (const __attribute__((address_space(1))) u32*)g,
        (__attribute__((address_space(3))) u32*)l, 16, 0, 0);
}

// ---------------- prepass: fp32 qkv -> bf16 LDS images in ws (unchanged r14) ----------------
__global__ __launch_bounds__(256)
void preconv(const float* __restrict__ qkv, char* __restrict__ ws)
{
    const int bid = blockIdx.x;        // bh*32 + kt
    const int bh = bid >> 5, kt = bid & 31;
    const int b = bh >> 5, h = bh & 31;
    char* img = ws + (size_t)bid * IMGB;

    const int t  = threadIdx.x;
    const int r  = t >> 2;             // key row in tile, 0..63
    const int cq = (t & 3) * 32;       // col base

    const float* kro = qkv + (size_t)(b * Sc + kt * 64 + r) * QKV_STRIDE
                       + Hc * Dc + h * Dc + cq;
    {
        short* kout = (short*)img + r * KST + cq;
        #pragma unroll
        for (int v = 0; v < 4; ++v) {
            float4 a = *(const float4*)(kro + v * 8);
            float4 c = *(const float4*)(kro + v * 8 + 4);
            bf16x8 pk;
            pk[0] = f2bf(a.x); pk[1] = f2bf(a.y); pk[2] = f2bf(a.z); pk[3] = f2bf(a.w);
            pk[4] = f2bf(c.x); pk[5] = f2bf(c.y); pk[6] = f2bf(c.z); pk[7] = f2bf(c.w);
            *(bf16x8*)(kout + v * 8) = pk;
        }
    }
    __shared__ float vt[64 * 129];
    {
        const float* vro = kro + Hc * Dc;
        #pragma unroll
        for (int v = 0; v < 8; ++v) {
            float4 a = *(const float4*)(vro + v * 4);
            float* dst = &vt[r * 129 + cq + v * 4];
            dst[0] = a.x; dst[1] = a.y; dst[2] = a.z; dst[3] = a.w;
        }
    }
    __syncthreads();
    {
        const int d = t >> 1, half = t & 1;
        short* vout = (short*)(img + V_OFF) + d * VST + half * 32;
        #pragma unroll
        for (int v = 0; v < 4; ++v) {
            bf16x8 pk;
            #pragma unroll
            for (int j = 0; j < 8; ++j)
                pk[j] = f2bf(vt[(half * 32 + v * 8 + j) * 129 + d]);
            *(bf16x8*)(vout + v * 8) = pk;
        }
    }
}

// ---------------- main kernel: DOUBLE-BUFFERED glds staging (T3 2-phase) ----------------
__global__ __launch_bounds__(256)
void attn_ws(const char* __restrict__ ws,
             const int* __restrict__ causal_p,
             const float* __restrict__ qkv,
             float* __restrict__ out)
{
    // Work-balanced 1D grid (r7)
    const int bid = blockIdx.x;
    const int o   = bid >> 6;
    const int bh  = bid & 63;
    const int r_  = o & 3;
    const int j_  = o >> 2;
    const int bq_ = 15 - 2 * r_;
    const int qt  = (j_ < 2) ? (bq_ - j_) : (15 - bq_ + 3 - j_);

    const int b = bh >> 5;
    const int h = bh & 31;
    const int causal = *causal_p;

    const int tid  = threadIdx.x;
    const int w    = tid >> 6;     // wave 0..3, owns 32 q rows
    const int lane = tid & 63;
    const int l31  = lane & 31;
    const int hf   = lane >> 5;

    __shared__ char lbuf[2 * IMGB];   // ping-pong LDS images

    const int q0  = qt * BQ;
    const int wq0 = q0 + w * 32;

    const char* imgs = ws + (size_t)bh * 32 * IMGB;

    // ---- Q as swapped-QK B-fragments (fp32 source, once) ----
    bf16x8 qf[8];
    {
        const float* qb = qkv + (size_t)(b * Sc + wq0 + l31) * QKV_STRIDE + h * Dc;
        #pragma unroll
        for (int st = 0; st < 8; ++st) {
            const float* p = qb + st * 16 + hf * 8;
            float4 x0 = *(const float4*)(p);
            float4 x1 = *(const float4*)(p + 4);
            bf16x8 q;
            q[0] = f2bf(x0.x * SCALE_LOG2E);
            q[1] = f2bf(x0.y * SCALE_LOG2E);
            q[2] = f2bf(x0.z * SCALE_LOG2E);
            q[3] = f2bf(x0.w * SCALE_LOG2E);
            q[4] = f2bf(x1.x * SCALE_LOG2E);
            q[5] = f2bf(x1.y * SCALE_LOG2E);
            q[6] = f2bf(x1.z * SCALE_LOG2E);
            q[7] = f2bf(x1.w * SCALE_LOG2E);
            qf[st] = q;
        }
    }

    f32x16 o_[4];
    #pragma unroll
    for (int db = 0; db < 4; ++db)
        #pragma unroll
        for (int i = 0; i < 16; ++i) o_[db][i] = 0.f;
    float m = -1e30f, l = 0.f;

    const int nkv = causal ? (2 * qt + 2) : (Sc / BK);

    // stage tile kt's image into buffer `buf` (wave w owns a 9KB slice)
    auto stage = [&](int kt, int buf) {
        const char* src = imgs + (size_t)kt * IMGB + w * 9216 + lane * 16;
        char* dst = lbuf + buf * IMGB + w * 9216;   // wave-uniform base
        #pragma unroll
        for (int i = 0; i < 9; ++i)
            glds16(src + i * 1024, dst + i * 1024);
    };

    // ---- prologue: tile 0 staged and published ----
    stage(0, 0);
    asm volatile("s_waitcnt vmcnt(0)" ::: "memory");
    __builtin_amdgcn_s_barrier();

    // ---- 2-phase main loop: STAGE(next) BEFORE compute(cur); single
    //      vmcnt(0)+barrier per tile AFTER compute (fetch hides under compute).
    //      Lifetimes: buf[cur]'s ds_reads drain at this iteration's lgkmcnt(0)
    //      before kt+1's glds rewrites it; glds for kt+1 drains at vmcnt(0)
    //      before the barrier that publishes it.
    for (int kt = 0; kt < nkv; ++kt) {
        const int cur = kt & 1;
        if (kt + 1 < nkv) stage(kt + 1, cur ^ 1);

        const int kbase = kt * BK;
        if (!(causal && kbase > wq0 + 31)) {
            const short* Ks = (const short*)(lbuf + cur * IMGB);
            const short* Vs = (const short*)(lbuf + cur * IMGB + V_OFF);

            // ---- S^T = K Q^T ----
            f32x16 acc[2];
            #pragma unroll
            for (int mb = 0; mb < 2; ++mb)
                #pragma unroll
                for (int i = 0; i < 16; ++i) acc[mb][i] = 0.f;
            __builtin_amdgcn_s_setprio(1);
            #pragma unroll
            for (int st = 0; st < 8; ++st) {
                #pragma unroll
                for (int mb = 0; mb < 2; ++mb) {
                    bf16x8 ka = *(const bf16x8*)&Ks[(mb * 32 + l31) * KST + st * 16 + hf * 8];
                    acc[mb] = __builtin_amdgcn_mfma_f32_32x32x16_bf16(ka, qf[st], acc[mb], 0, 0, 0);
                }
            }
            __builtin_amdgcn_s_setprio(0);

            // ---- causal mask (straddle tiles only) ----
            if (causal && kbase + 63 > wq0) {
                const int qg = wq0 + l31;
                #pragma unroll
                for (int mb = 0; mb < 2; ++mb) {
                    #pragma unroll
                    for (int r = 0; r < 16; ++r) {
                        const int kgl = kbase + mb * 32 + (r & 3) + 8 * (r >> 2) + 4 * hf;
                        if (kgl > qg) acc[mb][r] = -1e30f;
                    }
                }
            }

            // ---- online softmax; T13 defer ----
            float pm = acc[0][0];
            #pragma unroll
            for (int i = 1; i < 16; ++i) pm = fmaxf(pm, acc[0][i]);
            #pragma unroll
            for (int i = 0; i < 16; ++i) pm = fmaxf(pm, acc[1][i]);
            pm = fmaxf(pm, __shfl_xor(pm, 32));
            if (__any(pm > m + DEFER_THR)) {
                const float mnew  = fmaxf(m, pm);
                const float alpha = __builtin_amdgcn_exp2f(m - mnew);
                m = mnew; l *= alpha;
                #pragma unroll
                for (int r = 0; r < 16; ++r) {
                    const float ar = __shfl(alpha, (r & 3) + 8 * (r >> 2) + 4 * hf);
                    o_[0][r] *= ar; o_[1][r] *= ar; o_[2][r] *= ar; o_[3][r] *= ar;
                }
            }
            float rs = 0.f;
            #pragma unroll
            for (int i = 0; i < 16; ++i) {
                const float p = __builtin_amdgcn_exp2f(acc[0][i] - m);
                acc[0][i] = p; rs += p;
            }
            #pragma unroll
            for (int i = 0; i < 16; ++i) {
                const float p = __builtin_amdgcn_exp2f(acc[1][i] - m);
                acc[1][i] = p; rs += p;
            }
            rs += __shfl_xor(rs, 32);
            l += rs;

            // ---- P -> bf16 A-fragments (16 cvt_pk + 8 permlane, verified r12) ----
            unsigned wpk[2][4][2];
            #pragma unroll
            for (int mb = 0; mb < 2; ++mb)
                #pragma unroll
                for (int c = 0; c < 4; ++c) {
                    wpk[mb][c][0] = pk2(acc[mb][4 * c + 0], acc[mb][4 * c + 1]);
                    wpk[mb][c][1] = pk2(acc[mb][4 * c + 2], acc[mb][4 * c + 3]);
                }
            bf16x8 pa[4];
            #pragma unroll
            for (int ks = 0; ks < 4; ++ks) {
                const int mb = ks >> 1, ci = ks & 1;
                unsigned e0 = wpk[mb][2 * ci][0], o0 = wpk[mb][2 * ci + 1][0];
                unsigned e1 = wpk[mb][2 * ci][1], o1 = wpk[mb][2 * ci + 1][1];
                plswap(e0, o0);
                plswap(e1, o1);
                u32x4 wv;
                wv[0] = e0; wv[1] = e1; wv[2] = o0; wv[3] = o1;
                pa[ks] = __builtin_bit_cast(bf16x8, wv);
            }

            // ---- O += P V ----
            __builtin_amdgcn_s_setprio(1);
            #pragma unroll
            for (int ks = 0; ks < 4; ++ks) {
                #pragma unroll
                for (int db = 0; db < 4; ++db) {
                    bf16x8 vb = *(const bf16x8*)&Vs[(db * 32 + l31) * VST + ks * 16 + hf * 8];
                    o_[db] = __builtin_amdgcn_mfma_f32_32x32x16_bf16(pa[ks], vb, o_[db], 0, 0, 0);
                }
            }
            __builtin_amdgcn_s_setprio(0);
        }

        asm volatile("s_waitcnt vmcnt(0)" ::: "memory");  // next tile landed
        lds_barrier();                                    // publish; cur freed
    }

    // ---- epilogue ----
    #pragma unroll
    for (int r = 0; r < 16; ++r) {
        const int rq = (r & 3) + 8 * (r >> 2) + 4 * hf;
        const float lr = __shfl(l, rq);
        const float inv = 1.f / lr;
        const int qg = wq0 + rq;
        float* ob = out + (size_t)(b * Sc + qg) * (Hc * Dc) + h * Dc + l31;
        ob[0]  = o_[0][r] * inv;
        ob[32] = o_[1][r] * inv;
        ob[64] = o_[2][r] * inv;
        ob[96] = o_[3][r] * inv;
    }
}

// ---------------- fallback: r12 kernel verbatim (used if ws too small) ----------------
__global__ __launch_bounds__(256)
void attn_fb(const float* __restrict__ qkv,
             const int* __restrict__ causal_p,
             float* __restrict__ out)
{
    const int bid = blockIdx.x;
    const int o   = bid >> 6;
    const int bh  = bid & 63;
    const int r_  = o & 3;
    const int j_  = o >> 2;
    const int bq_ = 15 - 2 * r_;
    const int qt  = (j_ < 2) ? (bq_ - j_) : (15 - bq_ + 3 - j_);

    const int b = bh >> 5;
    const int h = bh & 31;
    const int causal = *causal_p;

    const int tid  = threadIdx.x;
    const int w    = tid >> 6;
    const int lane = tid & 63;
    const int l31  = lane & 31;
    const int hf   = lane >> 5;

    __shared__ short Ks[64 * KST];
    __shared__ short Vs[128 * VST];

    const int q0  = qt * BQ;
    const int wq0 = q0 + w * 32;
    const int kg = tid >> 5;
    const int dl = tid & 31;

    const float* kplane = qkv + (size_t)b * Sc * QKV_STRIDE + Hc * Dc + h * Dc;

    bf16x8 qf[8];
    {
        const float* qb = qkv + (size_t)(b * Sc + wq0 + l31) * QKV_STRIDE + h * Dc;
        #pragma unroll
        for (int st = 0; st < 8; ++st) {
            const float* p = qb + st * 16 + hf * 8;
            float4 x0 = *(const float4*)(p);
            float4 x1 = *(const float4*)(p + 4);
            bf16x8 q;
            q[0] = f2bf(x0.x * SCALE_LOG2E);
            q[1] = f2bf(x0.y * SCALE_LOG2E);
            q[2] = f2bf(x0.z * SCALE_LOG2E);
            q[3] = f2bf(x0.w * SCALE_LOG2E);
            q[4] = f2bf(x1.x * SCALE_LOG2E);
            q[5] = f2bf(x1.y * SCALE_LOG2E);
            q[6] = f2bf(x1.z * SCALE_LOG2E);
            q[7] = f2bf(x1.w * SCALE_LOG2E);
            qf[st] = q;
        }
    }

    f32x16 o_[4];
    #pragma unroll
    for (int db = 0; db < 4; ++db)
        #pragma unroll
        for (int i = 0; i < 16; ++i) o_[db][i] = 0.f;
    float m = -1e30f, l = 0.f;

    const int nkv = causal ? (2 * qt + 2) : (Sc / BK);
    float4 kst[8];
    float  vst[8][4];

    auto issue = [&](int kt) {
        const float* kb = kplane + (size_t)(kt * BK + kg * 8) * QKV_STRIDE;
        #pragma unroll
        for (int j = 0; j < 8; ++j)
            kst[j] = *(const float4*)(kb + (size_t)j * QKV_STRIDE + dl * 4);
        const float* vb = kb + Hc * Dc;
        #pragma unroll
        for (int j = 0; j < 8; ++j) {
            #pragma unroll
            for (int q = 0; q < 4; ++q)
                vst[j][q] = vb[(size_t)j * QKV_STRIDE + q * 32 + dl];
        }
    };
    auto commit = [&]() {
        #pragma unroll
        for (int j = 0; j < 8; ++j) {
            bf16x4 kk;
            kk[0] = f2bf(kst[j].x); kk[1] = f2bf(kst[j].y);
            kk[2] = f2bf(kst[j].z); kk[3] = f2bf(kst[j].w);
            *(bf16x4*)&Ks[(kg * 8 + j) * KST + dl * 4] = kk;
        }
        #pragma unroll
        for (int q = 0; q < 4; ++q) {
            bf16x8 vv;
            #pragma unroll
            for (int j = 0; j < 8; ++j) vv[j] = f2bf(vst[j][q]);
            *(bf16x8*)&Vs[(q * 32 + dl) * VST + kg * 8] = vv;
        }
    };

    issue(0);
    for (int kt = 0; kt < nkv; ++kt) {
        lds_barrier();
        commit();
        if (kt + 1 < nkv) issue(kt + 1);
        lds_barrier();

        const int kbase = kt * BK;
        if (causal && kbase > wq0 + 31) continue;

        f32x16 acc[2];
        #pragma unroll
        for (int mb = 0; mb < 2; ++mb)
            #pragma unroll
            for (int i = 0; i < 16; ++i) acc[mb][i] = 0.f;
        __builtin_amdgcn_s_setprio(1);
        #pragma unroll
        for (int st = 0; st < 8; ++st) {
            #pragma unroll
            for (int mb = 0; mb < 2; ++mb) {
                bf16x8 ka = *(const bf16x8*)&Ks[(mb * 32 + l31) * KST + st * 16 + hf * 8];
                acc[mb] = __builtin_amdgcn_mfma_f32_32x32x16_bf16(ka, qf[st], acc[mb], 0, 0, 0);
            }
        }
        __builtin_amdgcn_s_setprio(0);

        if (causal && kbase + 63 > wq0) {
            const int qg = wq0 + l31;
            #pragma unroll
            for (int mb = 0; mb < 2; ++mb) {
                #pragma unroll
                for (int r = 0; r < 16; ++r) {
                    const int kgl = kbase + mb * 32 + (r & 3) + 8 * (r >> 2) + 4 * hf;
                    if (kgl > qg) acc[mb][r] = -1e30f;
                }
            }
        }

        float pm = acc[0][0];
        #pragma unroll
        for (int i = 1; i < 16; ++i) pm = fmaxf(pm, acc[0][i]);
        #pragma unroll
        for (int i = 0; i < 16; ++i) pm = fmaxf(pm, acc[1][i]);
        pm = fmaxf(pm, __shfl_xor(pm, 32));
        if (__any(pm > m + DEFER_THR)) {
            const float mnew  = fmaxf(m, pm);
            const float alpha = __builtin_amdgcn_exp2f(m - mnew);
            m = mnew; l *= alpha;
            #pragma unroll
            for (int r = 0; r < 16; ++r) {
                const float ar = __shfl(alpha, (r & 3) + 8 * (r >> 2) + 4 * hf);
                o_[0][r] *= ar; o_[1][r] *= ar; o_[2][r] *= ar; o_[3][r] *= ar;
            }
        }
        float rs = 0.f;
        #pragma unroll
        for (int i = 0; i < 16; ++i) {
            const float p = __builtin_amdgcn_exp2f(acc[0][i] - m);
            acc[0][i] = p; rs += p;
        }
        #pragma unroll
        for (int i = 0; i < 16; ++i) {
            const float p = __builtin_amdgcn_exp2f(acc[1][i] - m);
            acc[1][i] = p; rs += p;
        }
        rs += __shfl_xor(rs, 32);
        l += rs;

        unsigned wpk[2][4][2];
        #pragma unroll
        for (int mb = 0; mb < 2; ++mb)
            #pragma unroll
            for (int c = 0; c < 4; ++c) {
                wpk[mb][c][0] = pk2(acc[mb][4 * c + 0], acc[mb][4 * c + 1]);
                wpk[mb][c][1] = pk2(acc[mb][4 * c + 2], acc[mb][4 * c + 3]);
            }
        bf16x8 pa[4];
        #pragma unroll
        for (int ks = 0; ks < 4; ++ks) {
            const int mb = ks >> 1, ci = ks & 1;
            unsigned e0 = wpk[mb][2 * ci][0], o0 = wpk[mb][2 * ci + 1][0];
            unsigned e1 = wpk[mb][2 * ci][1], o1 = wpk[mb][2 * ci + 1][1];
            plswap(e0, o0);
            plswap(e1, o1);
            u32x4 wv;
            wv[0] = e0; wv[1] = e1; wv[2] = o0; wv[3] = o1;
            pa[ks] = __builtin_bit_cast(bf16x8, wv);
        }

        __builtin_amdgcn_s_setprio(1);
        #pragma unroll
        for (int ks = 0; ks < 4; ++ks) {
            #pragma unroll
            for (int db = 0; db < 4; ++db) {
                bf16x8 vb = *(const bf16x8*)&Vs[(db * 32 + l31) * VST + ks * 16 + hf * 8];
                o_[db] = __builtin_amdgcn_mfma_f32_32x32x16_bf16(pa[ks], vb, o_[db], 0, 0, 0);
            }
        }
        __builtin_amdgcn_s_setprio(0);
    }

    #pragma unroll
    for (int r = 0; r < 16; ++r) {
        const int rq = (r & 3) + 8 * (r >> 2) + 4 * hf;
        const float lr = __shfl(l, rq);
        const float inv = 1.f / lr;
        const int qg = wq0 + rq;
        float* ob = out + (size_t)(b * Sc + qg) * (Hc * Dc) + h * Dc + l31;
        ob[0]  = o_[0][r] * inv;
        ob[32] = o_[1][r] * inv;
        ob[64] = o_[2][r] * inv;
        ob[96] = o_[3][r] * inv;
    }
}

extern "C" void kernel_launch(void* const* d_in, const int* in_sizes, int n_in,
                              void* d_out, int out_size, void* d_ws, size_t ws_size,
                              hipStream_t stream) {
    const float* qkv = (const float*)d_in[0];
    const int* causal = (const int*)d_in[1];
    float* out = (float*)d_out;
    if (ws_size >= WS_NEED) {
        preconv<<<Bc * Hc * (Sc / BK), 256, 0, stream>>>(qkv, (char*)d_ws);
        attn_ws<<<(Sc / BQ) * Bc * Hc, 256, 0, stream>>>((const char*)d_ws, causal, qkv, out);
    } else {
        attn_fb<<<(Sc / BQ) * Bc * Hc, 256, 0, stream>>>(qkv, causal, out);
    }
}

// Round 16
// 327.041 us; speedup vs baseline: 1.3364x; 1.2494x over previous
//
#include <hip/hip_runtime.h>
#include <hip/hip_bf16.h>

// Problem constants (reference: B,S,H,D = 2,2048,32,128)
constexpr int Bc = 2;
constexpr int Sc = 2048;
constexpr int Hc = 32;
constexpr int Dc = 128;
constexpr int QKV_STRIDE = 3 * Hc * Dc;   // floats per (b, s) row: 12288

constexpr int BQ = 128;  // query rows per block (4 waves x 32 rows)
constexpr int BK = 64;   // kv rows per tile
constexpr float SCALE_LOG2E = 0.088388347648318f * 1.442695040888963f;
constexpr float DEFER_THR = 8.0f;   // T13

// LDS strides (shorts) — measured conflict-free (r4-r15: SQ_LDS_BANK_CONFLICT = 0)
constexpr int KST = 132;   // K row 264B
constexpr int VST = 68;    // V row 136B

// Pre-staged LDS-image layout in d_ws, one image per (bh, kv-tile):
//   K section  [64][KST] bf16 @ 0       (16896 B)
//   V^T section[128][VST] bf16 @ 16896  (17408 B)
//   pad to 36864 B (= 4 waves x 9 x 1KB global_load_lds rounds)
constexpr int V_OFF = 64 * KST * 2;              // 16896
constexpr int IMGB  = 36864;
constexpr size_t WS_NEED = (size_t)Bc * Hc * (Sc / BK) * IMGB;  // 2048 images

typedef __attribute__((ext_vector_type(8)))  short    bf16x8;
typedef __attribute__((ext_vector_type(4)))  short    bf16x4;
typedef __attribute__((ext_vector_type(16))) float    f32x16;
typedef __attribute__((ext_vector_type(4)))  unsigned u32x4;
typedef unsigned int u32;

static __device__ __forceinline__ short f2bf(float f) {
    __bf16 h = (__bf16)f;                  // RNE; pairs into v_cvt_pk_bf16_f32
    return __builtin_bit_cast(short, h);
}
static __device__ __forceinline__ unsigned pk2(float lo, float hi) {
    union { short2 s; unsigned u; } x;
    x.s.x = f2bf(lo); x.s.y = f2bf(hi);
    return x.u;
}
// v_permlane32_swap_b32 (verified r12): after plswap(dst, src):
//   new_dst = [dst_lo, src_lo], new_src = [dst_hi, src_hi]
// Operands must hold DIFFERENT values (equal operands may coalesce -> no-op).
static __device__ __forceinline__ void plswap(unsigned& dst, unsigned& src) {
    asm volatile("v_permlane32_swap_b32 %0, %1" : "+v"(dst), "+v"(src));
}
// Raw barrier (lgkm drain only).
static __device__ __forceinline__ void lds_barrier() {
    asm volatile("s_waitcnt lgkmcnt(0)" ::: "memory");
    __builtin_amdgcn_s_barrier();
    asm volatile("" ::: "memory");
}
// Direct global->LDS copy, 16B per lane; LDS dest = wave-uniform base + lane*16.
static __device__ __forceinline__ void glds16(const char* g, char* l) {
    __builtin_amdgcn_global_load_lds(
        (const __attribute__((address_space(1))) u32*)g,
        (__attribute__((address_space(3))) u32*)l, 16, 0, 0);
}

// ---------------- prepass: fp32 qkv -> bf16 LDS images in ws (unchanged r14) ----------------
__global__ __launch_bounds__(256)
void preconv(const float* __restrict__ qkv, char* __restrict__ ws)
{
    const int bid = blockIdx.x;        // bh*32 + kt
    const int bh = bid >> 5, kt = bid & 31;
    const int b = bh >> 5, h = bh & 31;
    char* img = ws + (size_t)bid * IMGB;

    const int t  = threadIdx.x;
    const int r  = t >> 2;             // key row in tile, 0..63
    const int cq = (t & 3) * 32;       // col base

    const float* kro = qkv + (size_t)(b * Sc + kt * 64 + r) * QKV_STRIDE
                       + Hc * Dc + h * Dc + cq;
    {
        short* kout = (short*)img + r * KST + cq;
        #pragma unroll
        for (int v = 0; v < 4; ++v) {
            float4 a = *(const float4*)(kro + v * 8);
            float4 c = *(const float4*)(kro + v * 8 + 4);
            bf16x8 pk;
            pk[0] = f2bf(a.x); pk[1] = f2bf(a.y); pk[2] = f2bf(a.z); pk[3] = f2bf(a.w);
            pk[4] = f2bf(c.x); pk[5] = f2bf(c.y); pk[6] = f2bf(c.z); pk[7] = f2bf(c.w);
            *(bf16x8*)(kout + v * 8) = pk;
        }
    }
    __shared__ float vt[64 * 129];
    {
        const float* vro = kro + Hc * Dc;
        #pragma unroll
        for (int v = 0; v < 8; ++v) {
            float4 a = *(const float4*)(vro + v * 4);
            float* dst = &vt[r * 129 + cq + v * 4];
            dst[0] = a.x; dst[1] = a.y; dst[2] = a.z; dst[3] = a.w;
        }
    }
    __syncthreads();
    {
        const int d = t >> 1, half = t & 1;
        short* vout = (short*)(img + V_OFF) + d * VST + half * 32;
        #pragma unroll
        for (int v = 0; v < 4; ++v) {
            bf16x8 pk;
            #pragma unroll
            for (int j = 0; j < 8; ++j)
                pk[j] = f2bf(vt[(half * 32 + v * 8 + j) * 129 + d]);
            *(bf16x8*)(vout + v * 8) = pk;
        }
    }
}

// ---------------- main kernel: single-buffer glds + 4 blocks/CU (16 waves) ----------------
__global__ __launch_bounds__(256, 4)   // force VGPR <= 128 -> 4 blocks/CU co-resident
void attn_ws(const char* __restrict__ ws,
             const int* __restrict__ causal_p,
             const float* __restrict__ qkv,
             float* __restrict__ out)
{
    // Grid (1024) == residency capacity (256 CU x 4 blocks): ALL blocks
    // co-resident. Balance CONCURRENT classes c = o&3 (co-landing under any
    // stride-4-periodic assignment): qt in {15-c, c, 8+c, 7-c}, sum 30 each.
    const int bid = blockIdx.x;
    const int o   = bid >> 6;
    const int bh  = bid & 63;
    const int c_  = o & 3;
    const int j_  = o >> 2;
    const int qt  = (j_ == 0) ? (15 - c_) : (j_ == 1) ? c_
                  : (j_ == 2) ? (8 + c_)  : (7 - c_);

    const int b = bh >> 5;
    const int h = bh & 31;
    const int causal = *causal_p;

    const int tid  = threadIdx.x;
    const int w    = tid >> 6;     // wave 0..3, owns 32 q rows
    const int lane = tid & 63;
    const int l31  = lane & 31;
    const int hf   = lane >> 5;

    __shared__ char lbuf[IMGB];    // single image buffer (36.8 KB -> 4 blocks/CU)
    const short* Ks = (const short*)lbuf;
    const short* Vs = (const short*)(lbuf + V_OFF);

    const int q0  = qt * BQ;
    const int wq0 = q0 + w * 32;

    const char* imgs = ws + (size_t)bh * 32 * IMGB;

    // ---- Q as swapped-QK B-fragments (fp32 source, once) ----
    bf16x8 qf[8];
    {
        const float* qb = qkv + (size_t)(b * Sc + wq0 + l31) * QKV_STRIDE + h * Dc;
        #pragma unroll
        for (int st = 0; st < 8; ++st) {
            const float* p = qb + st * 16 + hf * 8;
            float4 x0 = *(const float4*)(p);
            float4 x1 = *(const float4*)(p + 4);
            bf16x8 q;
            q[0] = f2bf(x0.x * SCALE_LOG2E);
            q[1] = f2bf(x0.y * SCALE_LOG2E);
            q[2] = f2bf(x0.z * SCALE_LOG2E);
            q[3] = f2bf(x0.w * SCALE_LOG2E);
            q[4] = f2bf(x1.x * SCALE_LOG2E);
            q[5] = f2bf(x1.y * SCALE_LOG2E);
            q[6] = f2bf(x1.z * SCALE_LOG2E);
            q[7] = f2bf(x1.w * SCALE_LOG2E);
            qf[st] = q;
        }
    }

    f32x16 o_[4];
    #pragma unroll
    for (int db = 0; db < 4; ++db)
        #pragma unroll
        for (int i = 0; i < 16; ++i) o_[db][i] = 0.f;
    float m = -1e30f, l = 0.f;

    const int nkv = causal ? (2 * qt + 2) : (Sc / BK);

    for (int kt = 0; kt < nkv; ++kt) {
        lds_barrier();                      // prev tile's readers done
        {   // stage: wave w copies its 9KB slice of the pre-built image
            const char* src = imgs + (size_t)kt * IMGB + w * 9216 + lane * 16;
            char* dst = lbuf + w * 9216;    // wave-uniform
            #pragma unroll
            for (int i = 0; i < 9; ++i)
                glds16(src + i * 1024, dst + i * 1024);
        }
        asm volatile("s_waitcnt vmcnt(0)" ::: "memory");
        lds_barrier();                      // staged tile visible
        // (exposed stage within the block is hidden by the 3 other resident blocks)

        const int kbase = kt * BK;
        if (causal && kbase > wq0 + 31) continue;   // wave-uniform compute skip

        // ---- S^T = K Q^T ----
        f32x16 acc[2];
        #pragma unroll
        for (int mb = 0; mb < 2; ++mb)
            #pragma unroll
            for (int i = 0; i < 16; ++i) acc[mb][i] = 0.f;
        __builtin_amdgcn_s_setprio(1);
        #pragma unroll
        for (int st = 0; st < 8; ++st) {
            #pragma unroll
            for (int mb = 0; mb < 2; ++mb) {
                bf16x8 ka = *(const bf16x8*)&Ks[(mb * 32 + l31) * KST + st * 16 + hf * 8];
                acc[mb] = __builtin_amdgcn_mfma_f32_32x32x16_bf16(ka, qf[st], acc[mb], 0, 0, 0);
            }
        }
        __builtin_amdgcn_s_setprio(0);

        // ---- causal mask (straddle tiles only) ----
        if (causal && kbase + 63 > wq0) {
            const int qg = wq0 + l31;
            #pragma unroll
            for (int mb = 0; mb < 2; ++mb) {
                #pragma unroll
                for (int r = 0; r < 16; ++r) {
                    const int kgl = kbase + mb * 32 + (r & 3) + 8 * (r >> 2) + 4 * hf;
                    if (kgl > qg) acc[mb][r] = -1e30f;
                }
            }
        }

        // ---- online softmax; T13 defer ----
        float pm = acc[0][0];
        #pragma unroll
        for (int i = 1; i < 16; ++i) pm = fmaxf(pm, acc[0][i]);
        #pragma unroll
        for (int i = 0; i < 16; ++i) pm = fmaxf(pm, acc[1][i]);
        pm = fmaxf(pm, __shfl_xor(pm, 32));
        if (__any(pm > m + DEFER_THR)) {
            const float mnew  = fmaxf(m, pm);
            const float alpha = __builtin_amdgcn_exp2f(m - mnew);
            m = mnew; l *= alpha;
            #pragma unroll
            for (int r = 0; r < 16; ++r) {
                const float ar = __shfl(alpha, (r & 3) + 8 * (r >> 2) + 4 * hf);
                o_[0][r] *= ar; o_[1][r] *= ar; o_[2][r] *= ar; o_[3][r] *= ar;
            }
        }
        float rs = 0.f;
        #pragma unroll
        for (int i = 0; i < 16; ++i) {
            const float p = __builtin_amdgcn_exp2f(acc[0][i] - m);
            acc[0][i] = p; rs += p;
        }
        #pragma unroll
        for (int i = 0; i < 16; ++i) {
            const float p = __builtin_amdgcn_exp2f(acc[1][i] - m);
            acc[1][i] = p; rs += p;
        }
        rs += __shfl_xor(rs, 32);
        l += rs;

        // ---- P -> bf16 A-fragments (16 cvt_pk + 8 permlane, verified r12) ----
        unsigned wpk[2][4][2];
        #pragma unroll
        for (int mb = 0; mb < 2; ++mb)
            #pragma unroll
            for (int c = 0; c < 4; ++c) {
                wpk[mb][c][0] = pk2(acc[mb][4 * c + 0], acc[mb][4 * c + 1]);
                wpk[mb][c][1] = pk2(acc[mb][4 * c + 2], acc[mb][4 * c + 3]);
            }
        bf16x8 pa[4];
        #pragma unroll
        for (int ks = 0; ks < 4; ++ks) {
            const int mb = ks >> 1, ci = ks & 1;
            unsigned e0 = wpk[mb][2 * ci][0], o0 = wpk[mb][2 * ci + 1][0];
            unsigned e1 = wpk[mb][2 * ci][1], o1 = wpk[mb][2 * ci + 1][1];
            plswap(e0, o0);
            plswap(e1, o1);
            u32x4 wv;
            wv[0] = e0; wv[1] = e1; wv[2] = o0; wv[3] = o1;
            pa[ks] = __builtin_bit_cast(bf16x8, wv);
        }

        // ---- O += P V ----
        __builtin_amdgcn_s_setprio(1);
        #pragma unroll
        for (int ks = 0; ks < 4; ++ks) {
            #pragma unroll
            for (int db = 0; db < 4; ++db) {
                bf16x8 vb = *(const bf16x8*)&Vs[(db * 32 + l31) * VST + ks * 16 + hf * 8];
                o_[db] = __builtin_amdgcn_mfma_f32_32x32x16_bf16(pa[ks], vb, o_[db], 0, 0, 0);
            }
        }
        __builtin_amdgcn_s_setprio(0);
    }

    // ---- epilogue ----
    #pragma unroll
    for (int r = 0; r < 16; ++r) {
        const int rq = (r & 3) + 8 * (r >> 2) + 4 * hf;
        const float lr = __shfl(l, rq);
        const float inv = 1.f / lr;
        const int qg = wq0 + rq;
        float* ob = out + (size_t)(b * Sc + qg) * (Hc * Dc) + h * Dc + l31;
        ob[0]  = o_[0][r] * inv;
        ob[32] = o_[1][r] * inv;
        ob[64] = o_[2][r] * inv;
        ob[96] = o_[3][r] * inv;
    }
}

// ---------------- fallback: r12 kernel verbatim (used if ws too small) ----------------
__global__ __launch_bounds__(256)
void attn_fb(const float* __restrict__ qkv,
             const int* __restrict__ causal_p,
             float* __restrict__ out)
{
    const int bid = blockIdx.x;
    const int o   = bid >> 6;
    const int bh  = bid & 63;
    const int r_  = o & 3;
    const int j_  = o >> 2;
    const int bq_ = 15 - 2 * r_;
    const int qt  = (j_ < 2) ? (bq_ - j_) : (15 - bq_ + 3 - j_);

    const int b = bh >> 5;
    const int h = bh & 31;
    const int causal = *causal_p;

    const int tid  = threadIdx.x;
    const int w    = tid >> 6;
    const int lane = tid & 63;
    const int l31  = lane & 31;
    const int hf   = lane >> 5;

    __shared__ short Ks[64 * KST];
    __shared__ short Vs[128 * VST];

    const int q0  = qt * BQ;
    const int wq0 = q0 + w * 32;
    const int kg = tid >> 5;
    const int dl = tid & 31;

    const float* kplane = qkv + (size_t)b * Sc * QKV_STRIDE + Hc * Dc + h * Dc;

    bf16x8 qf[8];
    {
        const float* qb = qkv + (size_t)(b * Sc + wq0 + l31) * QKV_STRIDE + h * Dc;
        #pragma unroll
        for (int st = 0; st < 8; ++st) {
            const float* p = qb + st * 16 + hf * 8;
            float4 x0 = *(const float4*)(p);
            float4 x1 = *(const float4*)(p + 4);
            bf16x8 q;
            q[0] = f2bf(x0.x * SCALE_LOG2E);
            q[1] = f2bf(x0.y * SCALE_LOG2E);
            q[2] = f2bf(x0.z * SCALE_LOG2E);
            q[3] = f2bf(x0.w * SCALE_LOG2E);
            q[4] = f2bf(x1.x * SCALE_LOG2E);
            q[5] = f2bf(x1.y * SCALE_LOG2E);
            q[6] = f2bf(x1.z * SCALE_LOG2E);
            q[7] = f2bf(x1.w * SCALE_LOG2E);
            qf[st] = q;
        }
    }

    f32x16 o_[4];
    #pragma unroll
    for (int db = 0; db < 4; ++db)
        #pragma unroll
        for (int i = 0; i < 16; ++i) o_[db][i] = 0.f;
    float m = -1e30f, l = 0.f;

    const int nkv = causal ? (2 * qt + 2) : (Sc / BK);
    float4 kst[8];
    float  vst[8][4];

    auto issue = [&](int kt) {
        const float* kb = kplane + (size_t)(kt * BK + kg * 8) * QKV_STRIDE;
        #pragma unroll
        for (int j = 0; j < 8; ++j)
            kst[j] = *(const float4*)(kb + (size_t)j * QKV_STRIDE + dl * 4);
        const float* vb = kb + Hc * Dc;
        #pragma unroll
        for (int j = 0; j < 8; ++j) {
            #pragma unroll
            for (int q = 0; q < 4; ++q)
                vst[j][q] = vb[(size_t)j * QKV_STRIDE + q * 32 + dl];
        }
    };
    auto commit = [&]() {
        #pragma unroll
        for (int j = 0; j < 8; ++j) {
            bf16x4 kk;
            kk[0] = f2bf(kst[j].x); kk[1] = f2bf(kst[j].y);
            kk[2] = f2bf(kst[j].z); kk[3] = f2bf(kst[j].w);
            *(bf16x4*)&Ks[(kg * 8 + j) * KST + dl * 4] = kk;
        }
        #pragma unroll
        for (int q = 0; q < 4; ++q) {
            bf16x8 vv;
            #pragma unroll
            for (int j = 0; j < 8; ++j) vv[j] = f2bf(vst[j][q]);
            *(bf16x8*)&Vs[(q * 32 + dl) * VST + kg * 8] = vv;
        }
    };

    issue(0);
    for (int kt = 0; kt < nkv; ++kt) {
        lds_barrier();
        commit();
        if (kt + 1 < nkv) issue(kt + 1);
        lds_barrier();

        const int kbase = kt * BK;
        if (causal && kbase > wq0 + 31) continue;

        f32x16 acc[2];
        #pragma unroll
        for (int mb = 0; mb < 2; ++mb)
            #pragma unroll
            for (int i = 0; i < 16; ++i) acc[mb][i] = 0.f;
        __builtin_amdgcn_s_setprio(1);
        #pragma unroll
        for (int st = 0; st < 8; ++st) {
            #pragma unroll
            for (int mb = 0; mb < 2; ++mb) {
                bf16x8 ka = *(const bf16x8*)&Ks[(mb * 32 + l31) * KST + st * 16 + hf * 8];
                acc[mb] = __builtin_amdgcn_mfma_f32_32x32x16_bf16(ka, qf[st], acc[mb], 0, 0, 0);
            }
        }
        __builtin_amdgcn_s_setprio(0);

        if (causal && kbase + 63 > wq0) {
            const int qg = wq0 + l31;
            #pragma unroll
            for (int mb = 0; mb < 2; ++mb) {
                #pragma unroll
                for (int r = 0; r < 16; ++r) {
                    const int kgl = kbase + mb * 32 + (r & 3) + 8 * (r >> 2) + 4 * hf;
                    if (kgl > qg) acc[mb][r] = -1e30f;
                }
            }
        }

        float pm = acc[0][0];
        #pragma unroll
        for (int i = 1; i < 16; ++i) pm = fmaxf(pm, acc[0][i]);
        #pragma unroll
        for (int i = 0; i < 16; ++i) pm = fmaxf(pm, acc[1][i]);
        pm = fmaxf(pm, __shfl_xor(pm, 32));
        if (__any(pm > m + DEFER_THR)) {
            const float mnew  = fmaxf(m, pm);
            const float alpha = __builtin_amdgcn_exp2f(m - mnew);
            m = mnew; l *= alpha;
            #pragma unroll
            for (int r = 0; r < 16; ++r) {
                const float ar = __shfl(alpha, (r & 3) + 8 * (r >> 2) + 4 * hf);
                o_[0][r] *= ar; o_[1][r] *= ar; o_[2][r] *= ar; o_[3][r] *= ar;
            }
        }
        float rs = 0.f;
        #pragma unroll
        for (int i = 0; i < 16; ++i) {
            const float p = __builtin_amdgcn_exp2f(acc[0][i] - m);
            acc[0][i] = p; rs += p;
        }
        #pragma unroll
        for (int i = 0; i < 16; ++i) {
            const float p = __builtin_amdgcn_exp2f(acc[1][i] - m);
            acc[1][i] = p; rs += p;
        }
        rs += __shfl_xor(rs, 32);
        l += rs;

        unsigned wpk[2][4][2];
        #pragma unroll
        for (int mb = 0; mb < 2; ++mb)
            #pragma unroll
            for (int c = 0; c < 4; ++c) {
                wpk[mb][c][0] = pk2(acc[mb][4 * c + 0], acc[mb][4 * c + 1]);
                wpk[mb][c][1] = pk2(acc[mb][4 * c + 2], acc[mb][4 * c + 3]);
            }
        bf16x8 pa[4];
        #pragma unroll
        for (int ks = 0; ks < 4; ++ks) {
            const int mb = ks >> 1, ci = ks & 1;
            unsigned e0 = wpk[mb][2 * ci][0], o0 = wpk[mb][2 * ci + 1][0];
            unsigned e1 = wpk[mb][2 * ci][1], o1 = wpk[mb][2 * ci + 1][1];
            plswap(e0, o0);
            plswap(e1, o1);
            u32x4 wv;
            wv[0] = e0; wv[1] = e1; wv[2] = o0; wv[3] = o1;
            pa[ks] = __builtin_bit_cast(bf16x8, wv);
        }

        __builtin_amdgcn_s_setprio(1);
        #pragma unroll
        for (int ks = 0; ks < 4; ++ks) {
            #pragma unroll
            for (int db = 0; db < 4; ++db) {
                bf16x8 vb = *(const bf16x8*)&Vs[(db * 32 + l31) * VST + ks * 16 + hf * 8];
                o_[db] = __builtin_amdgcn_mfma_f32_32x32x16_bf16(pa[ks], vb, o_[db], 0, 0, 0);
            }
        }
        __builtin_amdgcn_s_setprio(0);
    }

    #pragma unroll
    for (int r = 0; r < 16; ++r) {
        const int rq = (r & 3) + 8 * (r >> 2) + 4 * hf;
        const float lr = __shfl(l, rq);
        const float inv = 1.f / lr;
        const int qg = wq0 + rq;
        float* ob = out + (size_t)(b * Sc + qg) * (Hc * Dc) + h * Dc + l31;
        ob[0]  = o_[0][r] * inv;
        ob[32] = o_[1][r] * inv;
        ob[64] = o_[2][r] * inv;
        ob[96] = o_[3][r] * inv;
    }
}

extern "C" void kernel_launch(void* const* d_in, const int* in_sizes, int n_in,
                              void* d_out, int out_size, void* d_ws, size_t ws_size,
                              hipStream_t stream) {
    const float* qkv = (const float*)d_in[0];
    const int* causal = (const int*)d_in[1];
    float* out = (float*)d_out;
    if (ws_size >= WS_NEED) {
        preconv<<<Bc * Hc * (Sc / BK), 256, 0, stream>>>(qkv, (char*)d_ws);
        attn_ws<<<(Sc / BQ) * Bc * Hc, 256, 0, stream>>>((const char*)d_ws, causal, qkv, out);
    } else {
        attn_fb<<<(Sc / BQ) * Bc * Hc, 256, 0, stream>>>(qkv, causal, out);
    }
}